// Round 2
// baseline (3682.512 us; speedup 1.0000x reference)
//
#include <hip/hip_runtime.h>

// RGCN 3-layer forward, MI355X.
// Per layer, loop over 8 relations: H_r = x @ Wrel[r] (bf16 MFMA GEMM, H_r bf16
// [N,128] = 25.6MB cache-resident), then scatter-add H_r[src] into fp32 Acc at dst
// (f32 atomics). Root transform initializes Acc. Edges compacted by type once.
// NOTE: harness passes ALL integer inputs as int32 (edge_index/edge_type are int*).
// Workspace use: ~90 MB.

#define DEVI __device__ __forceinline__

typedef __attribute__((ext_vector_type(8))) short bf16x8;
typedef __attribute__((ext_vector_type(4))) float f32x4;

DEVI unsigned short f2b(float f) {
  unsigned int u = __builtin_bit_cast(unsigned int, f);
  unsigned int r = (u + 0x7FFFu + ((u >> 16) & 1u)) >> 16;
  return (unsigned short)r;
}
DEVI float b2f(unsigned short h) {
  unsigned int u = ((unsigned int)h) << 16;
  return __builtin_bit_cast(float, u);
}

// ---------------- edge bucketing by type (8 bins) ----------------

__global__ void k_zero(int* cnt, int* cursor) {
  int t = threadIdx.x;
  if (t < 8) { cnt[t] = 0; cursor[t] = 0; }
}

__global__ void k_hist(const int* __restrict__ et, int* __restrict__ cnt, int E) {
  __shared__ int l[8];
  if (threadIdx.x < 8) l[threadIdx.x] = 0;
  __syncthreads();
  int stride = gridDim.x * blockDim.x;
  for (int i = blockIdx.x * blockDim.x + threadIdx.x; i < E; i += stride)
    atomicAdd(&l[et[i] & 7], 1);
  __syncthreads();
  if (threadIdx.x < 8) atomicAdd(&cnt[threadIdx.x], l[threadIdx.x]);
}

__global__ void k_offs(const int* __restrict__ cnt, int* __restrict__ offs) {
  if (threadIdx.x == 0) {
    int a = 0;
    for (int r = 0; r < 8; ++r) { offs[r] = a; a += cnt[r]; }
    offs[8] = a;
  }
}

__global__ void k_fill(const int* __restrict__ et, const int* __restrict__ esrc,
                       const int* __restrict__ edst, const int* __restrict__ offs,
                       int* __restrict__ cursor, int* __restrict__ src_c,
                       int* __restrict__ dst_c, int E) {
  __shared__ int lcnt[8], lbase[8], lcur[8];
  int e = blockIdx.x * 256 + threadIdx.x;
  if (threadIdx.x < 8) lcnt[threadIdx.x] = 0;
  __syncthreads();
  int t = 0;
  if (e < E) { t = et[e] & 7; atomicAdd(&lcnt[t], 1); }
  __syncthreads();
  if (threadIdx.x < 8) {
    lbase[threadIdx.x] = atomicAdd(&cursor[threadIdx.x], lcnt[threadIdx.x]);
    lcur[threadIdx.x] = 0;
  }
  __syncthreads();
  if (e < E) {
    int p = offs[t] + lbase[t] + atomicAdd(&lcur[t], 1);
    src_c[p] = esrc[e];
    dst_c[p] = edst[e];
  }
}

// ---------------- weight prep: fp32 [9][128][DOUT] -> bf16 transposed [9][DOUT][128] ----------------

__global__ void wprep_kernel(const float* __restrict__ Wrel, const float* __restrict__ Wroot,
                             unsigned short* __restrict__ wt, int DOUT) {
  int total = 9 * 128 * DOUT;
  int stride = gridDim.x * blockDim.x;
  for (int i = blockIdx.x * blockDim.x + threadIdx.x; i < total; i += stride) {
    int k = i & 127;
    int oo = i >> 7;           // rr*DOUT + o
    int o = oo % DOUT;
    int rr = oo / DOUT;
    float v = (rr < 8) ? Wrel[((size_t)rr * 128 + k) * DOUT + o]
                       : Wroot[(size_t)k * DOUT + o];
    wt[i] = f2b(v);
  }
}

// ---------------- GEMM: [nrows,128](bf16) x [128,DOUT] -> H_r (bf16) or Acc (f32 + bias) ----------------

template <int DOUT>
__launch_bounds__(256)
__global__ void gemm_kernel(const unsigned short* __restrict__ xb,
                            const unsigned short* __restrict__ wt,  // [9*DOUT*128] bf16, [o][k]
                            int rr,                                 // 0..7 rel, 8 root
                            const float* __restrict__ bias,         // non-null => root path
                            unsigned short* __restrict__ Hout,
                            float* __restrict__ Acc,
                            int nrows) {
  __shared__ unsigned short wl[DOUT * 136];   // padded [o][k] to dodge bank conflicts
  const unsigned short* wsrc = wt + (size_t)rr * DOUT * 128;
  for (int pch = threadIdx.x; pch < DOUT * 16; pch += 256) {
    int o = pch >> 4;
    int kc = (pch & 15) << 3;
    bf16x8 v = *(const bf16x8*)(wsrc + o * 128 + kc);
    *(bf16x8*)(wl + o * 136 + kc) = v;
  }
  __syncthreads();

  int wid = threadIdx.x >> 6, lane = threadIdx.x & 63;
  int colb = lane & 15, kgrp = lane >> 4;
  int rowbase = blockIdx.x * 128 + wid * 32;   // 4 waves x 32 rows = 128 rows/block

  f32x4 acc[2][DOUT / 16];
#pragma unroll
  for (int t = 0; t < 2; ++t)
#pragma unroll
    for (int nf = 0; nf < DOUT / 16; ++nf) {
      f32x4 z = {0.f, 0.f, 0.f, 0.f};
      acc[t][nf] = z;
    }

  int r0 = rowbase + colb;
  int r1 = r0 + 16;
  int r0c = r0 < nrows ? r0 : 0;
  int r1c = r1 < nrows ? r1 : 0;

#pragma unroll
  for (int kk = 0; kk < 4; ++kk) {
    int kbase = kk * 32 + kgrp * 8;
    bf16x8 a0 = *(const bf16x8*)(xb + (size_t)r0c * 128 + kbase);
    bf16x8 a1 = *(const bf16x8*)(xb + (size_t)r1c * 128 + kbase);
#pragma unroll
    for (int nf = 0; nf < DOUT / 16; ++nf) {
      bf16x8 b = *(const bf16x8*)(wl + (nf * 16 + colb) * 136 + kbase);
      acc[0][nf] = __builtin_amdgcn_mfma_f32_16x16x32_bf16(a0, b, acc[0][nf], 0, 0, 0);
      acc[1][nf] = __builtin_amdgcn_mfma_f32_16x16x32_bf16(a1, b, acc[1][nf], 0, 0, 0);
    }
  }

  int rsub = kgrp * 4;
#pragma unroll
  for (int t = 0; t < 2; ++t) {
#pragma unroll
    for (int i = 0; i < 4; ++i) {
      int row = rowbase + t * 16 + rsub + i;
      if (row >= nrows) continue;
#pragma unroll
      for (int nf = 0; nf < DOUT / 16; ++nf) {
        int col = nf * 16 + colb;
        float v = acc[t][nf][i];
        if (bias) Acc[(size_t)row * DOUT + col] = v + bias[col];
        else Hout[(size_t)row * DOUT + col] = f2b(v);
      }
    }
  }
}

// ---------------- edge scatter: Acc[dst] += H_r[src], one wave per edge ----------------

template <int DOUT>
__global__ void scatter_kernel(const int* __restrict__ offs, const int* __restrict__ src_c,
                               const int* __restrict__ dst_c,
                               const unsigned short* __restrict__ H,
                               float* __restrict__ acc, int rel) {
  int lane = threadIdx.x & 63;
  int wid = (blockIdx.x * blockDim.x + threadIdx.x) >> 6;
  int nw = (gridDim.x * blockDim.x) >> 6;
  int lo = offs[rel], hi = offs[rel + 1];
  for (int i = lo + wid; i < hi; i += nw) {
    int s = src_c[i], d = dst_c[i];
    if (DOUT == 128) {
      unsigned int v = *(const unsigned int*)(H + (size_t)s * 128 + lane * 2);
      atomicAdd(&acc[(size_t)d * 128 + lane * 2 + 0], b2f((unsigned short)(v & 0xFFFFu)));
      atomicAdd(&acc[(size_t)d * 128 + lane * 2 + 1], b2f((unsigned short)(v >> 16)));
    } else {
      atomicAdd(&acc[(size_t)d * 64 + lane], b2f(H[(size_t)s * 64 + lane]));
    }
  }
}

// ---------------- cast / relu-cast, log-softmax ----------------

__global__ void cast_kernel(const float* __restrict__ in, unsigned short* __restrict__ out,
                            int n4, int do_relu) {
  int stride = gridDim.x * blockDim.x;
  for (int i = blockIdx.x * blockDim.x + threadIdx.x; i < n4; i += stride) {
    float4 v = ((const float4*)in)[i];
    if (do_relu) {
      v.x = fmaxf(v.x, 0.f); v.y = fmaxf(v.y, 0.f);
      v.z = fmaxf(v.z, 0.f); v.w = fmaxf(v.w, 0.f);
    }
    ushort4 o;
    o.x = f2b(v.x); o.y = f2b(v.y); o.z = f2b(v.z); o.w = f2b(v.w);
    ((ushort4*)out)[i] = o;
  }
}

__global__ void lsm_kernel(const float* __restrict__ acc, float* __restrict__ out, int nrows) {
  int lane = threadIdx.x & 63;
  int row = (blockIdx.x * blockDim.x + threadIdx.x) >> 6;
  if (row >= nrows) return;
  float v = acc[(size_t)row * 64 + lane];
  float m = v;
#pragma unroll
  for (int s = 32; s; s >>= 1) m = fmaxf(m, __shfl_xor(m, s));
  float e = __expf(v - m);
  float sum = e;
#pragma unroll
  for (int s = 32; s; s >>= 1) sum += __shfl_xor(sum, s);
  out[(size_t)row * 64 + lane] = v - m - __logf(sum);
}

// ---------------- launch ----------------

extern "C" void kernel_launch(void* const* d_in, const int* in_sizes, int n_in,
                              void* d_out, int out_size, void* d_ws, size_t ws_size,
                              hipStream_t stream) {
  const float* x = (const float*)d_in[0];
  const int* eidx = (const int*)d_in[1];     // int32 (harness converts integer inputs)
  const int* et = (const int*)d_in[2];       // int32
  const float* Wrel1 = (const float*)d_in[3];
  const float* Wroot1 = (const float*)d_in[4];
  const float* b1 = (const float*)d_in[5];
  const float* Wrel2 = (const float*)d_in[6];
  const float* Wroot2 = (const float*)d_in[7];
  const float* b2 = (const float*)d_in[8];
  const float* Wrel3 = (const float*)d_in[9];
  const float* Wroot3 = (const float*)d_in[10];
  const float* b3 = (const float*)d_in[11];

  const int N = in_sizes[0] / 128;    // 100000
  const int E = in_sizes[2];          // 1600000
  const int* esrc = eidx;
  const int* edst = eidx + E;

  char* p = (char*)d_ws;
  auto carve = [&](size_t bytes) {
    void* q = (void*)p;
    p += (bytes + 255) & ~(size_t)255;
    return q;
  };
  unsigned short* bufX = (unsigned short*)carve((size_t)N * 128 * 2);  // current features (bf16)
  unsigned short* bufH = (unsigned short*)carve((size_t)N * 128 * 2);  // per-relation transform
  float* Acc = (float*)carve((size_t)N * 128 * 4);
  unsigned short* wt = (unsigned short*)carve((size_t)9 * 128 * 128 * 2);
  int* src_c = (int*)carve((size_t)E * 4);
  int* dst_c = (int*)carve((size_t)E * 4);
  int* cnt = (int*)carve(64);
  int* offs = (int*)carve(64);
  int* cursor = (int*)carve(64);

  // ---- bucket edges by relation (once; reused by all 3 layers) ----
  k_zero<<<1, 64, 0, stream>>>(cnt, cursor);
  k_hist<<<1024, 256, 0, stream>>>(et, cnt, E);
  k_offs<<<1, 1, 0, stream>>>(cnt, offs);
  k_fill<<<(E + 255) / 256, 256, 0, stream>>>(et, esrc, edst, offs, cursor, src_c, dst_c, E);

  // ---- input cast fp32 -> bf16 ----
  cast_kernel<<<2048, 256, 0, stream>>>(x, bufX, N * 128 / 4, 0);

  const int gemmGrid = (N + 127) / 128;

  // ---- layer 1 (128 -> 128, relu) ----
  wprep_kernel<<<576, 256, 0, stream>>>(Wrel1, Wroot1, wt, 128);
  gemm_kernel<128><<<gemmGrid, 256, 0, stream>>>(bufX, wt, 8, b1, (unsigned short*)nullptr, Acc, N);
  for (int r = 0; r < 8; ++r) {
    gemm_kernel<128><<<gemmGrid, 256, 0, stream>>>(bufX, wt, r, (const float*)nullptr, bufH, Acc, N);
    scatter_kernel<128><<<1024, 256, 0, stream>>>(offs, src_c, dst_c, bufH, Acc, r);
  }
  cast_kernel<<<2048, 256, 0, stream>>>(Acc, bufX, N * 128 / 4, 1);

  // ---- layer 2 (128 -> 128, relu) ----
  wprep_kernel<<<576, 256, 0, stream>>>(Wrel2, Wroot2, wt, 128);
  gemm_kernel<128><<<gemmGrid, 256, 0, stream>>>(bufX, wt, 8, b2, (unsigned short*)nullptr, Acc, N);
  for (int r = 0; r < 8; ++r) {
    gemm_kernel<128><<<gemmGrid, 256, 0, stream>>>(bufX, wt, r, (const float*)nullptr, bufH, Acc, N);
    scatter_kernel<128><<<1024, 256, 0, stream>>>(offs, src_c, dst_c, bufH, Acc, r);
  }
  cast_kernel<<<2048, 256, 0, stream>>>(Acc, bufX, N * 128 / 4, 1);

  // ---- layer 3 (128 -> 64, log_softmax) ----
  wprep_kernel<<<288, 256, 0, stream>>>(Wrel3, Wroot3, wt, 64);
  gemm_kernel<64><<<gemmGrid, 256, 0, stream>>>(bufX, wt, 8, b3, (unsigned short*)nullptr, Acc, N);
  for (int r = 0; r < 8; ++r) {
    gemm_kernel<64><<<gemmGrid, 256, 0, stream>>>(bufX, wt, r, (const float*)nullptr, bufH, Acc, N);
    scatter_kernel<64><<<1024, 256, 0, stream>>>(offs, src_c, dst_c, bufH, Acc, r);
  }
  lsm_kernel<<<(N * 64 + 255) / 256, 256, 0, stream>>>(Acc, (float*)d_out, N);
}

// Round 3
// 1059.437 us; speedup vs baseline: 3.4759x; 3.4759x over previous
//
#include <hip/hip_runtime.h>

// RGCN 3-layer forward, MI355X.
// Per layer: root GEMM writes Acc = x@Wroot+b; then for each batch of nh relations:
// batched bf16 MFMA GEMM computes H_r = x@Wrel[r] (bf16 [N,128] each, L3-resident),
// then an atomic-free segmented gather-sum (edges counting-sorted by rel*N+dst once
// per call) does Acc[d] += sum_r sum_{e in seg(r,d)} H_r[src_e] with ONE plain RMW
// per row. No global atomics on the feature path (round-2 counters showed 200MB HBM
// write-through per atomic scatter dispatch = 90% of runtime).
// NOTE: harness passes integer inputs as int32.

#define DEVI __device__ __forceinline__

typedef __attribute__((ext_vector_type(8))) short bf16x8;
typedef __attribute__((ext_vector_type(4))) float f32x4;

DEVI unsigned short f2b(float f) {
  unsigned int u = __builtin_bit_cast(unsigned int, f);
  unsigned int r = (u + 0x7FFFu + ((u >> 16) & 1u)) >> 16;
  return (unsigned short)r;
}
DEVI float b2f(unsigned short h) {
  unsigned int u = ((unsigned int)h) << 16;
  return __builtin_bit_cast(float, u);
}

// ---------------- counting sort of edges by key = rel*N + dst ----------------

__global__ void k_zero2(int* __restrict__ cnt, int n) {
  int stride = gridDim.x * blockDim.x;
  for (int i = blockIdx.x * blockDim.x + threadIdx.x; i < n; i += stride) cnt[i] = 0;
}

__global__ void k_hist2(const int* __restrict__ et, const int* __restrict__ edst,
                        int* __restrict__ cnt, int N, int E) {
  int stride = gridDim.x * blockDim.x;
  for (int i = blockIdx.x * blockDim.x + threadIdx.x; i < E; i += stride)
    atomicAdd(&cnt[(et[i] & 7) * N + edst[i]], 1);
}

// block-local exclusive scan; block totals to bsum
__global__ void k_scan1(const int* __restrict__ cnt, int* __restrict__ offs,
                        int* __restrict__ bsum, int KT) {
  __shared__ int l[256];
  int g = blockIdx.x * 256 + threadIdx.x;
  int v = (g < KT) ? cnt[g] : 0;
  l[threadIdx.x] = v;
  __syncthreads();
  for (int o = 1; o < 256; o <<= 1) {
    int t = (threadIdx.x >= o) ? l[threadIdx.x - o] : 0;
    __syncthreads();
    l[threadIdx.x] += t;
    __syncthreads();
  }
  if (g < KT) offs[g] = l[threadIdx.x] - v;
  if (threadIdx.x == 255) bsum[blockIdx.x] = l[255];
}

// single-block exclusive scan of block sums (nb up to a few thousand)
__global__ void k_scan2(int* __restrict__ bsum, int nb) {
  __shared__ int l[256];
  __shared__ int carry;
  if (threadIdx.x == 0) carry = 0;
  __syncthreads();
  for (int base = 0; base < nb; base += 256) {
    int g = base + threadIdx.x;
    int v = (g < nb) ? bsum[g] : 0;
    l[threadIdx.x] = v;
    __syncthreads();
    for (int o = 1; o < 256; o <<= 1) {
      int t = (threadIdx.x >= o) ? l[threadIdx.x - o] : 0;
      __syncthreads();
      l[threadIdx.x] += t;
      __syncthreads();
    }
    if (g < nb) bsum[g] = l[threadIdx.x] - v + carry;
    __syncthreads();
    if (threadIdx.x == 0) carry += l[255];
    __syncthreads();
  }
}

__global__ void k_scan3(int* __restrict__ offs, const int* __restrict__ bsum,
                        int* __restrict__ cursor, int KT, int E) {
  int g = blockIdx.x * 256 + threadIdx.x;
  if (g < KT) {
    int v = offs[g] + bsum[blockIdx.x];
    offs[g] = v;
    cursor[g] = v;
  }
  if (g == 0) offs[KT] = E;
}

__global__ void k_fill2(const int* __restrict__ et, const int* __restrict__ esrc,
                        const int* __restrict__ edst, int* __restrict__ cursor,
                        int* __restrict__ src_s, int N, int E) {
  int stride = gridDim.x * blockDim.x;
  for (int i = blockIdx.x * blockDim.x + threadIdx.x; i < E; i += stride) {
    int key = (et[i] & 7) * N + edst[i];
    int pos = atomicAdd(&cursor[key], 1);
    src_s[pos] = esrc[i];
  }
}

// ---------------- weight prep: fp32 [9][128][DOUT] -> bf16 transposed [9][DOUT][128] ----------------

__global__ void wprep_kernel(const float* __restrict__ Wrel, const float* __restrict__ Wroot,
                             unsigned short* __restrict__ wt, int DOUT) {
  int total = 9 * 128 * DOUT;
  int stride = gridDim.x * blockDim.x;
  for (int i = blockIdx.x * blockDim.x + threadIdx.x; i < total; i += stride) {
    int k = i & 127;
    int oo = i >> 7;           // rr*DOUT + o
    int o = oo % DOUT;
    int rr = oo / DOUT;
    float v = (rr < 8) ? Wrel[((size_t)rr * 128 + k) * DOUT + o]
                       : Wroot[(size_t)k * DOUT + o];
    wt[i] = f2b(v);
  }
}

// ---------------- GEMM: [N,128](bf16) x [128,DOUT] -> H[blockIdx.y] (bf16) or Acc (f32+bias) ----------------

template <int DOUT>
__launch_bounds__(256)
__global__ void gemm_kernel(const unsigned short* __restrict__ xb,
                            const unsigned short* __restrict__ wt,  // [9*DOUT*128] bf16, [o][k]
                            int r0,                                 // rel base; 8 = root
                            const float* __restrict__ bias,         // non-null => root path
                            unsigned short* __restrict__ Hout,      // base of H buffers
                            float* __restrict__ Acc,
                            int nrows) {
  __shared__ unsigned short wl[DOUT * 136];
  int rr = r0 + blockIdx.y;
  unsigned short* Hw = Hout + (size_t)blockIdx.y * nrows * DOUT;
  const unsigned short* wsrc = wt + (size_t)rr * DOUT * 128;
  for (int pch = threadIdx.x; pch < DOUT * 16; pch += 256) {
    int o = pch >> 4;
    int kc = (pch & 15) << 3;
    bf16x8 v = *(const bf16x8*)(wsrc + o * 128 + kc);
    *(bf16x8*)(wl + o * 136 + kc) = v;
  }
  __syncthreads();

  int wid = threadIdx.x >> 6, lane = threadIdx.x & 63;
  int colb = lane & 15, kgrp = lane >> 4;
  int rowbase = blockIdx.x * 128 + wid * 32;

  f32x4 acc[2][DOUT / 16];
#pragma unroll
  for (int t = 0; t < 2; ++t)
#pragma unroll
    for (int nf = 0; nf < DOUT / 16; ++nf) {
      f32x4 z = {0.f, 0.f, 0.f, 0.f};
      acc[t][nf] = z;
    }

  int r0r = rowbase + colb;
  int r1r = r0r + 16;
  int r0c = r0r < nrows ? r0r : 0;
  int r1c = r1r < nrows ? r1r : 0;

#pragma unroll
  for (int kk = 0; kk < 4; ++kk) {
    int kbase = kk * 32 + kgrp * 8;
    bf16x8 a0 = *(const bf16x8*)(xb + (size_t)r0c * 128 + kbase);
    bf16x8 a1 = *(const bf16x8*)(xb + (size_t)r1c * 128 + kbase);
#pragma unroll
    for (int nf = 0; nf < DOUT / 16; ++nf) {
      bf16x8 b = *(const bf16x8*)(wl + (nf * 16 + colb) * 136 + kbase);
      acc[0][nf] = __builtin_amdgcn_mfma_f32_16x16x32_bf16(a0, b, acc[0][nf], 0, 0, 0);
      acc[1][nf] = __builtin_amdgcn_mfma_f32_16x16x32_bf16(a1, b, acc[1][nf], 0, 0, 0);
    }
  }

  int rsub = kgrp * 4;
#pragma unroll
  for (int t = 0; t < 2; ++t) {
#pragma unroll
    for (int i = 0; i < 4; ++i) {
      int row = rowbase + t * 16 + rsub + i;
      if (row >= nrows) continue;
#pragma unroll
      for (int nf = 0; nf < DOUT / 16; ++nf) {
        int col = nf * 16 + colb;
        float v = acc[t][nf][i];
        if (bias) Acc[(size_t)row * DOUT + col] = v + bias[col];
        else Hw[(size_t)row * DOUT + col] = f2b(v);
      }
    }
  }
}

// ---------------- segmented gather-sum: Acc[d] += sum over nh relations' segments ----------------

template <int DOUT>
__global__ void gather_kernel(const int* __restrict__ offs, const int* __restrict__ src_s,
                              const unsigned short* __restrict__ H,  // [nh][N*DOUT]
                              float* __restrict__ acc, int r0, int nh, int N) {
  int lane = threadIdx.x & 63;
  int d = (blockIdx.x * blockDim.x + threadIdx.x) >> 6;
  if (d >= N) return;
  float s0 = 0.f, s1 = 0.f;
  for (int rr = 0; rr < nh; ++rr) {
    const unsigned short* Hb = H + (size_t)rr * N * DOUT;
    int key = (r0 + rr) * N + d;
    int lo = offs[key], hi = offs[key + 1];
    int i = lo;
    if (DOUT == 128) {
      for (; i + 4 <= hi; i += 4) {
        int sA = src_s[i], sB = src_s[i + 1], sC = src_s[i + 2], sD = src_s[i + 3];
        unsigned vA = *(const unsigned*)(Hb + (size_t)sA * 128 + lane * 2);
        unsigned vB = *(const unsigned*)(Hb + (size_t)sB * 128 + lane * 2);
        unsigned vC = *(const unsigned*)(Hb + (size_t)sC * 128 + lane * 2);
        unsigned vD = *(const unsigned*)(Hb + (size_t)sD * 128 + lane * 2);
        s0 += b2f((unsigned short)(vA & 0xFFFFu)) + b2f((unsigned short)(vB & 0xFFFFu))
            + b2f((unsigned short)(vC & 0xFFFFu)) + b2f((unsigned short)(vD & 0xFFFFu));
        s1 += b2f((unsigned short)(vA >> 16)) + b2f((unsigned short)(vB >> 16))
            + b2f((unsigned short)(vC >> 16)) + b2f((unsigned short)(vD >> 16));
      }
      for (; i < hi; ++i) {
        int s = src_s[i];
        unsigned v = *(const unsigned*)(Hb + (size_t)s * 128 + lane * 2);
        s0 += b2f((unsigned short)(v & 0xFFFFu));
        s1 += b2f((unsigned short)(v >> 16));
      }
    } else {
      for (; i + 4 <= hi; i += 4) {
        int sA = src_s[i], sB = src_s[i + 1], sC = src_s[i + 2], sD = src_s[i + 3];
        s0 += b2f(Hb[(size_t)sA * 64 + lane]) + b2f(Hb[(size_t)sB * 64 + lane])
            + b2f(Hb[(size_t)sC * 64 + lane]) + b2f(Hb[(size_t)sD * 64 + lane]);
      }
      for (; i < hi; ++i) s0 += b2f(Hb[(size_t)src_s[i] * 64 + lane]);
    }
  }
  if (DOUT == 128) {
    float* a = acc + (size_t)d * 128 + lane * 2;
    a[0] += s0;
    a[1] += s1;
  } else {
    acc[(size_t)d * 64 + lane] += s0;
  }
}

// ---------------- cast / relu-cast, log-softmax ----------------

__global__ void cast_kernel(const float* __restrict__ in, unsigned short* __restrict__ out,
                            int n4, int do_relu) {
  int stride = gridDim.x * blockDim.x;
  for (int i = blockIdx.x * blockDim.x + threadIdx.x; i < n4; i += stride) {
    float4 v = ((const float4*)in)[i];
    if (do_relu) {
      v.x = fmaxf(v.x, 0.f); v.y = fmaxf(v.y, 0.f);
      v.z = fmaxf(v.z, 0.f); v.w = fmaxf(v.w, 0.f);
    }
    ushort4 o;
    o.x = f2b(v.x); o.y = f2b(v.y); o.z = f2b(v.z); o.w = f2b(v.w);
    ((ushort4*)out)[i] = o;
  }
}

__global__ void lsm_kernel(const float* __restrict__ acc, float* __restrict__ out, int nrows) {
  int lane = threadIdx.x & 63;
  int row = (blockIdx.x * blockDim.x + threadIdx.x) >> 6;
  if (row >= nrows) return;
  float v = acc[(size_t)row * 64 + lane];
  float m = v;
#pragma unroll
  for (int s = 32; s; s >>= 1) m = fmaxf(m, __shfl_xor(m, s));
  float e = __expf(v - m);
  float sum = e;
#pragma unroll
  for (int s = 32; s; s >>= 1) sum += __shfl_xor(sum, s);
  out[(size_t)row * 64 + lane] = v - m - __logf(sum);
}

// ---------------- launch ----------------

extern "C" void kernel_launch(void* const* d_in, const int* in_sizes, int n_in,
                              void* d_out, int out_size, void* d_ws, size_t ws_size,
                              hipStream_t stream) {
  const float* x = (const float*)d_in[0];
  const int* eidx = (const int*)d_in[1];     // int32 (harness converts integer inputs)
  const int* et = (const int*)d_in[2];       // int32
  const float* Wrel1 = (const float*)d_in[3];
  const float* Wroot1 = (const float*)d_in[4];
  const float* b1 = (const float*)d_in[5];
  const float* Wrel2 = (const float*)d_in[6];
  const float* Wroot2 = (const float*)d_in[7];
  const float* b2 = (const float*)d_in[8];
  const float* Wrel3 = (const float*)d_in[9];
  const float* Wroot3 = (const float*)d_in[10];
  const float* b3 = (const float*)d_in[11];

  const int N = in_sizes[0] / 128;    // 100000
  const int E = in_sizes[2];          // 1600000
  const int KT = 8 * N;
  const int* esrc = eidx;
  const int* edst = eidx + E;

  char* p = (char*)d_ws;
  auto carve = [&](size_t bytes) {
    void* q = (void*)p;
    p += (bytes + 255) & ~(size_t)255;
    return q;
  };
  unsigned short* bufX = (unsigned short*)carve((size_t)N * 128 * 2);  // current features (bf16)
  float* Acc = (float*)carve((size_t)N * 128 * 4);
  unsigned short* wt = (unsigned short*)carve((size_t)9 * 128 * 128 * 2);
  int* src_s = (int*)carve((size_t)E * 4);
  int* cnt = (int*)carve((size_t)KT * 4);
  int* offs = (int*)carve((size_t)(KT + 1) * 4);
  int* cursor = (int*)carve((size_t)KT * 4);
  const int nbs = (KT + 255) / 256;
  int* bsum = (int*)carve((size_t)nbs * 4);

  // adaptive H-batch count based on remaining workspace
  size_t used = (size_t)(p - (char*)d_ws);
  size_t avail = (ws_size > used) ? ws_size - used : 0;
  size_t Hbytes = (size_t)N * 128 * 2;
  int nh = 4;
  while (nh > 1 && (size_t)nh * (Hbytes + 256) > avail) nh >>= 1;
  unsigned short* Hbuf = (unsigned short*)carve((size_t)nh * Hbytes);

  // ---- counting sort of edges by rel*N+dst (once; reused by all 3 layers) ----
  k_zero2<<<2048, 256, 0, stream>>>(cnt, KT);
  k_hist2<<<2048, 256, 0, stream>>>(et, edst, cnt, N, E);
  k_scan1<<<nbs, 256, 0, stream>>>(cnt, offs, bsum, KT);
  k_scan2<<<1, 256, 0, stream>>>(bsum, nbs);
  k_scan3<<<nbs, 256, 0, stream>>>(offs, bsum, cursor, KT, E);
  k_fill2<<<2048, 256, 0, stream>>>(et, esrc, edst, cursor, src_s, N, E);

  // ---- input cast fp32 -> bf16 ----
  cast_kernel<<<2048, 256, 0, stream>>>(x, bufX, N * 128 / 4, 0);

  const int gemmGrid = (N + 127) / 128;
  const int gatherGrid = (N + 3) / 4;   // 4 waves (dsts) per 256-thread block

  // ---- layer 1 (128 -> 128, relu) ----
  wprep_kernel<<<576, 256, 0, stream>>>(Wrel1, Wroot1, wt, 128);
  gemm_kernel<128><<<dim3(gemmGrid, 1), 256, 0, stream>>>(bufX, wt, 8, b1, (unsigned short*)nullptr, Acc, N);
  for (int r0 = 0; r0 < 8; r0 += nh) {
    gemm_kernel<128><<<dim3(gemmGrid, nh), 256, 0, stream>>>(bufX, wt, r0, (const float*)nullptr, Hbuf, Acc, N);
    gather_kernel<128><<<gatherGrid, 256, 0, stream>>>(offs, src_s, Hbuf, Acc, r0, nh, N);
  }
  cast_kernel<<<2048, 256, 0, stream>>>(Acc, bufX, N * 128 / 4, 1);

  // ---- layer 2 (128 -> 128, relu) ----
  wprep_kernel<<<576, 256, 0, stream>>>(Wrel2, Wroot2, wt, 128);
  gemm_kernel<128><<<dim3(gemmGrid, 1), 256, 0, stream>>>(bufX, wt, 8, b2, (unsigned short*)nullptr, Acc, N);
  for (int r0 = 0; r0 < 8; r0 += nh) {
    gemm_kernel<128><<<dim3(gemmGrid, nh), 256, 0, stream>>>(bufX, wt, r0, (const float*)nullptr, Hbuf, Acc, N);
    gather_kernel<128><<<gatherGrid, 256, 0, stream>>>(offs, src_s, Hbuf, Acc, r0, nh, N);
  }
  cast_kernel<<<2048, 256, 0, stream>>>(Acc, bufX, N * 128 / 4, 1);

  // ---- layer 3 (128 -> 64, log_softmax) ----
  wprep_kernel<<<288, 256, 0, stream>>>(Wrel3, Wroot3, wt, 64);
  gemm_kernel<64><<<dim3(gemmGrid, 1), 256, 0, stream>>>(bufX, wt, 8, b3, (unsigned short*)nullptr, Acc, N);
  for (int r0 = 0; r0 < 8; r0 += nh) {
    gemm_kernel<64><<<dim3(gemmGrid, nh), 256, 0, stream>>>(bufX, wt, r0, (const float*)nullptr, Hbuf, Acc, N);
    gather_kernel<64><<<gatherGrid, 256, 0, stream>>>(offs, src_s, Hbuf, Acc, r0, nh, N);
  }
  lsm_kernel<<<(N * 64 + 255) / 256, 256, 0, stream>>>(Acc, (float*)d_out, N);
}